// Round 4
// baseline (1234.058 us; speedup 1.0000x reference)
//
#include <hip/hip_runtime.h>
#include <math.h>

// ---------------- problem constants ----------------
#define NB 16
#define TT 12
#define H1 47
#define W1D 46
#define H2 46
#define W2D 44

typedef short short8v __attribute__((ext_vector_type(8)));
typedef float floatx4 __attribute__((ext_vector_type(4)));
typedef unsigned long long u64;

__device__ __forceinline__ short f2bf(float x) {
    unsigned u = __float_as_uint(x);
    u = (u + 0x7FFFu + ((u >> 16) & 1u)) >> 16;   // RNE
    return (short)u;
}
__device__ __forceinline__ float bf2f(short s) {
    return __uint_as_float(((unsigned)(unsigned short)s) << 16);
}
__device__ __forceinline__ float hsig(float z) {
    return fminf(fmaxf(0.2f * z + 0.5f, 0.f), 1.f);
}

// Cache-bypassing 8B load/store: commits/reads at the memory-side LLC,
// coherent across XCDs. No L2 writeback/invalidate anywhere.
__device__ __forceinline__ u64 ld_cc(const u64* p) {
    return __hip_atomic_load(p, __ATOMIC_RELAXED, __HIP_MEMORY_SCOPE_AGENT);
}
__device__ __forceinline__ void st_cc(u64* p, u64 v) {
    __hip_atomic_store(p, v, __ATOMIC_RELAXED, __HIP_MEMORY_SCOPE_AGENT);
}

// ---------------------------------------------------------------------------
// Weights -> MFMA B-fragment layout, bf16.
// flat idx = ((c*2+fh)*4+g)*512 + j*32 + ci ; column = g*32+fh*16+j, k = ci
// ---------------------------------------------------------------------------
__global__ __launch_bounds__(256) void transform_w(
    const float* __restrict__ W1s, const float* __restrict__ U1s,
    const float* __restrict__ W2s, const float* __restrict__ U2s,
    short* __restrict__ Bt1, short* __restrict__ Bt2)
{
    int idx = blockIdx.x * 256 + threadIdx.x;       // 0..77823
    int layer2 = idx >= 28672;
    int i = layer2 ? idx - 28672 : idx;
    int ci = i & 31, j = (i >> 5) & 15, g = (i >> 9) & 3, fh = (i >> 11) & 1, c = i >> 12;
    int col = g * 32 + fh * 16 + j;
    float v = 0.f;
    if (!layer2) {
        if (c == 0) {
            if (ci < 18) { int kk = ci / 3, cc = ci - kk * 3; v = W1s[(kk * 3 + cc) * 128 + col]; }
        } else {
            v = U1s[((c - 1) * 32 + ci) * 128 + col];
        }
    } else {
        if (c < 6) v = W2s[(c * 32 + ci) * 128 + col];
        else       v = U2s[((c - 6) * 32 + ci) * 128 + col];
    }
    (layer2 ? Bt2 : Bt1)[i] = f2bf(v);
}

// ---------------------------------------------------------------------------
// One ConvLSTM tile (6 rows x 16 cols) for one engine (128 thr = 2 fh waves).
// c-state register-resident. Cross-block h traffic via bypass (ld_cc/st_cc).
// ---------------------------------------------------------------------------
template<int LAYER>
__device__ __forceinline__ void step_body(
    const float* __restrict__ xf,      // L1: raw float x
    const short* __restrict__ xin,     // L2: h1(t) slot (bf16)
    const short* __restrict__ hprev,   // recurrent h(t-1) slot (bf16)
    const short* __restrict__ Bt,
    const float* __restrict__ bias,
    floatx4* cst,                      // register-resident [6]
    short* __restrict__ hnext,
    short* __restrict__ pool, int t,
    int b, int y0, int x0, short* ldsrec, short* ldsaux, short* ldsH, int etid)
{
    constexpr int Ho   = (LAYER == 1) ? H1 : H2;
    constexpr int Wo   = (LAYER == 1) ? W1D : W2D;
    constexpr int NCH  = (LAYER == 1) ? 7 : 12;
    constexpr int REC0 = (LAYER == 1) ? 1 : 6;
    constexpr int HBS  = Ho * Wo * 32;

    const int lane = etid & 63;
    const int fh = etid >> 6;
    const int tx = lane & 15, q = lane >> 4;

    // ---- stage recurrent tile: rows y0..y0+6, cols x0-1..x0+16, SAME-pad zeros ----
    {
        const short* hb0 = hprev + b * HBS;
        for (int i = etid; i < 1008; i += 128) {      // 126 pos x 8 chunks(8B)
            int p = i >> 3, c8 = i & 7;
            int row = p / 18, col = p - row * 18;
            int y = y0 + row, xx = x0 + col - 1;
            u64 v = 0;
            if (y < Ho && (unsigned)xx < (unsigned)Wo)
                v = ld_cc((const u64*)(hb0 + (y * Wo + xx) * 32) + c8);
            *((u64*)&ldsrec[p * 40] + c8) = v;
        }
    }

    if (LAYER == 1) {
        // padded im2col of x chunk 0: m=0..95 (6x16 tile), k=kk*3+cc (18 -> pad 32)
        const float* xb0 = xf + b * (TT * 48 * 48 * 3) + t * 6912;
        for (int i = etid; i < 96 * 32; i += 128) {
            int m = i >> 5, k = i & 31;
            short v = 0;
            if (k < 18) {
                int kk = k / 3, cc = k - kk * 3;
                int ky = (kk >= 3) ? 1 : 0, kx = kk - ky * 3;
                int ys = y0 + (m >> 4) + ky; if (ys > 47) ys = 47;
                int xs = x0 + (m & 15) + kx; if (xs > 47) xs = 47;
                v = f2bf(xb0[(ys * 48 + xs) * 3 + cc]);
            }
            ldsaux[m * 40 + k] = v;
        }
    } else {
        // stage input-conv source tile: rows y0..y0+6 (clamped), cols x0..x0+17
        // (OOB cols fall in slot slack; garbage feeds only masked outputs)
        const short* ib0 = xin + b * (H1 * W1D * 32);
        for (int i = etid; i < 1008; i += 128) {
            int p = i >> 3, c8 = i & 7;
            int row = p / 18, col = p - row * 18;
            int ys = y0 + row; if (ys > H1 - 1) ys = H1 - 1;
            int xs = x0 + col;
            u64 v = ld_cc((const u64*)(ib0 + (ys * W1D + xs) * 32) + c8);
            *((u64*)&ldsaux[p * 40] + c8) = v;
        }
    }
    __syncthreads();

    const short* Btl = Bt + fh * 2048 + tx * 32 + q * 8;
    floatx4 acc[6][4] = {};   // [a(row)][gate]

#pragma unroll
    for (int c = 0; c < NCH; ++c) {
        short8v bf4[4], af[6];
#pragma unroll
        for (int g = 0; g < 4; ++g)
            bf4[g] = *(const short8v*)(Btl + c * 4096 + g * 512);

        if (LAYER == 1 && c == 0) {
#pragma unroll
            for (int a = 0; a < 6; ++a)
                af[a] = *(const short8v*)&ldsaux[(a * 16 + tx) * 40 + q * 8];
        } else if (LAYER == 2 && c < REC0) {
            int ky = (c >= 3) ? 1 : 0, kx = c - ky * 3;
#pragma unroll
            for (int a = 0; a < 6; ++a)
                af[a] = *(const short8v*)&ldsaux[(((a + ky) * 18 + tx + kx)) * 40 + q * 8];
        } else {
            int kk = c - REC0;
            int ky = (kk >= 3) ? 1 : 0, kx = kk - ky * 3;
#pragma unroll
            for (int a = 0; a < 6; ++a)
                af[a] = *(const short8v*)&ldsrec[(((a + ky) * 18 + tx + kx)) * 40 + q * 8];
        }
#pragma unroll
        for (int a = 0; a < 6; ++a)
#pragma unroll
            for (int g = 0; g < 4; ++g)
                acc[a][g] = __builtin_amdgcn_mfma_f32_16x16x32_bf16(af[a], bf4[g], acc[a][g], 0, 0, 0);
    }

    // ---- fused LSTM epilogue (C layout: M=q*4+r -> x, N=tx(+fh*16) -> f) ----
    const int f = fh * 16 + tx;
    const float bi = bias[f], bfv = bias[32 + f], bcv = bias[64 + f], bov = bias[96 + f];
    float hv[6][4];
#pragma unroll
    for (int a = 0; a < 6; ++a) {
        floatx4 cold = cst[a];
        floatx4 cnew;
#pragma unroll
        for (int r = 0; r < 4; ++r) {
            float ig = hsig(acc[a][0][r] + bi);
            float fg = hsig(acc[a][1][r] + bfv);
            float gg = fmaxf(acc[a][2][r] + bcv, 0.f);
            float og = hsig(acc[a][3][r] + bov);
            float cn = fg * cold[r] + ig * gg;
            cnew[r] = cn;
            short hb = f2bf(og * fmaxf(cn, 0.f));
            ldsH[(a * 16 + q * 4 + r) * 36 + f] = hb;
            hv[a][r] = bf2f(hb);
        }
        cst[a] = cnew;
    }
    __syncthreads();   // ldsH complete (both waves of every engine)

    // ---- stream h tile out via bypass stores (skip masked rows/cols) ----
    {
        short* hb_out = hnext + b * HBS;
        for (int j = etid; j < 768; j += 128) {       // 96 pos x 8 chunks(8B)
            int pos = j >> 3, c8 = j & 7;
            int y = y0 + (pos >> 4), xx = x0 + (pos & 15);
            if (y < Ho && xx < Wo)
                st_cc((u64*)(hb_out + (y * Wo + xx) * 32) + c8,
                      *((const u64*)&ldsH[pos * 36] + c8));
        }
    }

    if (LAYER == 2) {
        // MaxPool(2,2): row pairs (0,1),(2,3),(4,5); col pairs within r
#pragma unroll
        for (int ap = 0; ap < 3; ++ap) {
            int py = y0 / 2 + ap;
#pragma unroll
            for (int rp = 0; rp < 2; ++rp) {
                int px = x0 / 2 + q * 2 + rp;
                if (py < 23 && px < 22) {
                    float m = fmaxf(fmaxf(hv[2 * ap][2 * rp],     hv[2 * ap][2 * rp + 1]),
                                    fmaxf(hv[2 * ap + 1][2 * rp], hv[2 * ap + 1][2 * rp + 1]));
                    pool[(size_t)b * 194304 + ((t * 23 + py) * 22 + px) * 32 + f] = f2bf(m);
                }
            }
        }
    }
}

__device__ __forceinline__ int fidx(int L, int bb, int hh) {
    return (L * 32 + bb * 2 + hh) * 16;
}

// ---------------------------------------------------------------------------
// Persistent coarse-grained pipeline. grid = 64 x 512 thr.
// gid: layer = gid&1 ; b = (gid>>1)&15 ; half = gid>>5 (rows 0..23 / 24..47).
// Block = 4 engines (2 waves each); engine e owns row band ty = half*4+e,
// iterating x0 in {0,16,32}. c-state cst[3][6] in registers.
// h1/h2 are 3-slot rings (slot = t mod 3) giving 2 steps of WAR slack so
// L1 free-runs ahead of L2 and flag latency hides under compute.
// Waits (flag = completed steps of a block):
//  L1 top:  botL1>=t        ; L2(b,0)>=t-2 ; L2(b,1)>=t-2   (WAR on h1 ring)
//  L1 bot:  topL1>=t-1 (WAR); L2(b,0)>=t-2 ; L2(b,1)>=t-2
//  L2 top:  L1(b,0)>=t+1 ; L1(b,1)>=t+1 ; botL2>=t   (halo, covers WAR)
//  L2 bot:  L1(b,0)>=t+1 ; L1(b,1)>=t+1 ; topL2>=t-1 (WAR on h2 ring)
// DAG (rank 2t+layer) -> no cycles; 64 blocks always co-resident -> no hang.
// ---------------------------------------------------------------------------
__global__ __launch_bounds__(512, 2) void fused_persistent(
    const float* __restrict__ x,
    short* __restrict__ h1s0, short* __restrict__ h1s1, short* __restrict__ h1s2,
    short* __restrict__ h2s0, short* __restrict__ h2s1, short* __restrict__ h2s2,
    const short* __restrict__ Bt1, const short* __restrict__ Bt2,
    const float* __restrict__ b1, const float* __restrict__ b2,
    short* __restrict__ pool, int* __restrict__ prog)
{
    __shared__ short lds[54144];          // 4 engines x (rec 5040 + aux 5040 + H 3456)
    const int tid = threadIdx.x;
    const int e = tid >> 7, etid = tid & 127;
    int gid   = blockIdx.x;
    int layer = gid & 1;
    int b     = (gid >> 1) & 15;
    int half  = gid >> 5;
    int y0 = (half * 4 + e) * 6;
    short* eb = lds + e * 13536;
    short* ldsrec = eb, * ldsaux = eb + 5040, * ldsH = eb + 10080;

    int fA, fB, fC, dA, dB, dC, myf;
    if (layer == 0) {
        if (half == 0) { fA = fidx(0, b, 1); dA = 0;  }
        else           { fA = fidx(0, b, 0); dA = -1; }
        fB = fidx(1, b, 0); dB = -2;
        fC = fidx(1, b, 1); dC = -2;
        myf = fidx(0, b, half);
    } else {
        fA = fidx(0, b, 0); dA = 1;
        fB = fidx(0, b, 1); dB = 1;
        if (half == 0) { fC = fidx(1, b, 1); dC = 0;  }
        else           { fC = fidx(1, b, 0); dC = -1; }
        myf = fidx(1, b, half);
    }

    floatx4 cst[3][6];
#pragma unroll
    for (int v = 0; v < 3; ++v)
#pragma unroll
        for (int a = 0; a < 6; ++a) cst[v][a] = (floatx4)0.f;

    for (int t = 0; t < TT; ++t) {
        // ---- wait on (at most 3) producer/WAR flags: lanes 0..2 spin ----
        if (tid < 3) {
            int fi = (tid == 0) ? fA : ((tid == 1) ? fB : fC);
            int dd = (tid == 0) ? dA : ((tid == 1) ? dB : dC);
            int tg = t + dd;
            if (tg >= 1) {
                const int* pp = prog + fi;
                while (__hip_atomic_load(pp, __ATOMIC_RELAXED, __HIP_MEMORY_SCOPE_AGENT) < tg)
                    __builtin_amdgcn_s_sleep(4);
            }
        }
        __syncthreads();

        int sw = t % 3, sr = (t + 2) % 3;   // write slot, recurrent-read slot
        short* h1w = (sw == 0) ? h1s0 : ((sw == 1) ? h1s1 : h1s2);
        short* h1r = (sr == 0) ? h1s0 : ((sr == 1) ? h1s1 : h1s2);
        short* h2w = (sw == 0) ? h2s0 : ((sw == 1) ? h2s1 : h2s2);
        short* h2r = (sr == 0) ? h2s0 : ((sr == 1) ? h2s1 : h2s2);

        if (layer == 0) {
#pragma unroll
            for (int v = 0; v < 3; ++v)
                step_body<1>(x, nullptr, h1r, Bt1, b1, cst[v], h1w, nullptr, t,
                             b, y0, v * 16, ldsrec, ldsaux, ldsH, etid);
        } else {
#pragma unroll
            for (int v = 0; v < 3; ++v)
                step_body<2>(nullptr, h1w, h2r, Bt2, b2, cst[v], h2w, pool, t,
                             b, y0, v * 16, ldsrec, ldsaux, ldsH, etid);
        }

        // all bypass stores drained (vmcnt(0) before s_barrier), then publish
        __syncthreads();
        if (tid == 0)
            __hip_atomic_store(prog + myf, t + 1, __ATOMIC_RELAXED, __HIP_MEMORY_SCOPE_AGENT);
    }
}

// ---------------------------------------------------------------------------
__global__ __launch_bounds__(256) void gemv_kernel(
    const short* __restrict__ p, const float* __restrict__ Wd1, float* __restrict__ d1)
{
    int by = blockIdx.y;                 // batch group: 4*by .. 4*by+3
    int k0 = blockIdx.x * 3036;          // 194304 / 64
    float part[4][10];
#pragma unroll
    for (int bb = 0; bb < 4; bb++)
#pragma unroll
        for (int j = 0; j < 10; j++) part[bb][j] = 0.f;

    for (int k = k0 + threadIdx.x; k < k0 + 3036; k += 256) {
        const float* wr = Wd1 + (size_t)k * 10;
        float wv[10];
#pragma unroll
        for (int j = 0; j < 10; j++) wv[j] = wr[j];
#pragma unroll
        for (int bb = 0; bb < 4; bb++) {
            float m = bf2f(p[(size_t)(by * 4 + bb) * 194304 + k]);
#pragma unroll
            for (int j = 0; j < 10; j++) part[bb][j] = fmaf(m, wv[j], part[bb][j]);
        }
    }
    __shared__ float red[4][10][4];
    int lane = threadIdx.x & 63, wv2 = threadIdx.x >> 6;
#pragma unroll
    for (int bb = 0; bb < 4; bb++)
#pragma unroll
        for (int j = 0; j < 10; j++) {
            float v = part[bb][j];
            for (int off = 32; off > 0; off >>= 1) v += __shfl_down(v, off);
            if (lane == 0) red[bb][j][wv2] = v;
        }
    __syncthreads();
    if (threadIdx.x < 40) {
        int bb = threadIdx.x / 10, j = threadIdx.x % 10;
        float s = red[bb][j][0] + red[bb][j][1] + red[bb][j][2] + red[bb][j][3];
        atomicAdd(&d1[(by * 4 + bb) * 10 + j], s);
    }
}

__global__ void final_dense(const float* __restrict__ d1, const float* __restrict__ bd1,
                            const float* __restrict__ Wd2, const float* __restrict__ bd2,
                            float* __restrict__ out)
{
    int b = threadIdx.x;
    if (b < NB) {
        float s = bd2[0];
#pragma unroll
        for (int j = 0; j < 10; j++) s += (d1[b * 10 + j] + bd1[j]) * Wd2[j];
        out[b] = s;
    }
}

// ---------------------------------------------------------------------------
extern "C" void kernel_launch(void* const* d_in, const int* in_sizes, int n_in,
                              void* d_out, int out_size, void* d_ws, size_t ws_size,
                              hipStream_t stream)
{
    const float* x   = (const float*)d_in[0];
    const float* W1s = (const float*)d_in[1];
    const float* U1s = (const float*)d_in[2];
    const float* b1  = (const float*)d_in[3];
    const float* W2s = (const float*)d_in[4];
    const float* U2s = (const float*)d_in[5];
    const float* b2  = (const float*)d_in[6];
    const float* Wd1 = (const float*)d_in[7];
    const float* bd1 = (const float*)d_in[8];
    const float* Wd2 = (const float*)d_in[9];
    const float* bd2 = (const float*)d_in[10];
    float* out = (float*)d_out;

    const int H1N = NB * H1 * W1D * 32;   // 1106944
    const int H2N = NB * H2 * W2D * 32;   // 1036288
    const int SLF = 32, SLB = 8192;
    const int SPAN1 = SLF + H1N + SLB;
    const int SPAN2 = SLF + H2N + SLB;

    short* Bt1 = (short*)d_ws;            // 28672
    short* Bt2 = Bt1 + 28672;             // 49152
    short* p   = Bt2 + 49152;             // 3108864
    short* zr  = p + 3108864;             // ---- zero region ----
    short* h1s0 = zr + 0 * SPAN1 + SLF;
    short* h1s1 = zr + 1 * SPAN1 + SLF;
    short* h1s2 = zr + 2 * SPAN1 + SLF;
    short* h2b  = zr + 3 * SPAN1;
    short* h2s0 = h2b + 0 * SPAN2 + SLF;
    short* h2s1 = h2b + 1 * SPAN2 + SLF;
    short* h2s2 = h2b + 2 * SPAN2 + SLF;
    float* d1  = (float*)(zr + 3 * SPAN1 + 3 * SPAN2);
    int* prog  = (int*)(d1 + 160);        // 64 flags x 16 ints
    size_t zero_bytes = (size_t)(3 * SPAN1 + 3 * SPAN2) * 2 + 160 * 4 + 1024 * 4;

    hipMemsetAsync(zr, 0, zero_bytes, stream);
    transform_w<<<304, 256, 0, stream>>>(W1s, U1s, W2s, U2s, Bt1, Bt2);

    // single persistent launch: coarse blocks, flag-pipelined layers
    fused_persistent<<<dim3(64), 512, 0, stream>>>(
        x, h1s0, h1s1, h1s2, h2s0, h2s1, h2s2, Bt1, Bt2, b1, b2, p, prog);

    gemv_kernel<<<dim3(64, 4), 256, 0, stream>>>(p, Wd1, d1);
    final_dense<<<1, 64, 0, stream>>>(d1, bd1, Wd2, bd2, out);
}

// Round 5
// 371.048 us; speedup vs baseline: 3.3259x; 3.3259x over previous
//
#include <hip/hip_runtime.h>
#include <math.h>

// ---------------- problem constants ----------------
#define NB 16
#define TT 12
#define H1 47
#define W1D 46
#define H2 46
#define W2D 44
#define NBLK 768

typedef short short8v __attribute__((ext_vector_type(8)));
typedef float floatx4 __attribute__((ext_vector_type(4)));
typedef unsigned int u32x4 __attribute__((ext_vector_type(4)));

__device__ __forceinline__ short f2bf(float x) {
    unsigned u = __float_as_uint(x);
    u = (u + 0x7FFFu + ((u >> 16) & 1u)) >> 16;   // RNE
    return (short)u;
}
__device__ __forceinline__ float bf2f(short s) {
    return __uint_as_float(((unsigned)(unsigned short)s) << 16);
}
__device__ __forceinline__ float hsig(float z) {
    return fminf(fmaxf(0.2f * z + 0.5f, 0.f), 1.f);
}

// ---- plain (non-atomic) cache-bypassing VMEM ops: coalesce + pipeline, ----
// ---- served at the memory-side LLC which is coherent across XCDs.       ----
#define GLOAD16(dst, addr) \
    asm volatile("global_load_dwordx4 %0, %1, off sc0 sc1" : "=v"(dst) : "v"(addr))
#define GSTORE16(addr, val) \
    asm volatile("global_store_dwordx4 %0, %1, off sc0 sc1" :: "v"(addr), "v"(val) : "memory")
#define VMWAIT() do { asm volatile("s_waitcnt vmcnt(0)" ::: "memory"); \
                      __builtin_amdgcn_sched_barrier(0); } while (0)

__device__ __forceinline__ int ldflag(const int* p) {
    int r;
    asm volatile("global_load_dword %0, %1, off sc0 sc1\n\ts_waitcnt vmcnt(0)"
                 : "=v"(r) : "v"(p) : "memory");
    return r;
}

// ---------------------------------------------------------------------------
// Weights -> MFMA B-fragment layout, bf16.
// flat idx = ((c*2+fh)*4+g)*512 + j*32 + ci ; column = g*32+fh*16+j, k = ci
// ---------------------------------------------------------------------------
__global__ __launch_bounds__(256) void transform_w(
    const float* __restrict__ W1s, const float* __restrict__ U1s,
    const float* __restrict__ W2s, const float* __restrict__ U2s,
    short* __restrict__ Bt1, short* __restrict__ Bt2)
{
    int idx = blockIdx.x * 256 + threadIdx.x;       // 0..77823
    int layer2 = idx >= 28672;
    int i = layer2 ? idx - 28672 : idx;
    int ci = i & 31, j = (i >> 5) & 15, g = (i >> 9) & 3, fh = (i >> 11) & 1, c = i >> 12;
    int col = g * 32 + fh * 16 + j;
    float v = 0.f;
    if (!layer2) {
        if (c == 0) {
            if (ci < 18) { int kk = ci / 3, cc = ci - kk * 3; v = W1s[(kk * 3 + cc) * 128 + col]; }
        } else {
            v = U1s[((c - 1) * 32 + ci) * 128 + col];
        }
    } else {
        if (c < 6) v = W2s[(c * 32 + ci) * 128 + col];
        else       v = U2s[((c - 6) * 32 + ci) * 128 + col];
    }
    (layer2 ? Bt2 : Bt1)[i] = f2bf(v);
}

// ---------------------------------------------------------------------------
// One ConvLSTM timestep body. 128 threads = 2 waves (fh halves).
// Tile 6 rows x 16 cols; wave M=96 (6 row-frags), N=64 (4 gates x 16 f).
// c-state in registers. Cross-block h traffic via 16B bypass asm ops.
// ---------------------------------------------------------------------------
template<int LAYER>
__device__ __forceinline__ void step_body(
    const float* __restrict__ xf,      // L1: raw float x
    const short* __restrict__ xin,     // L2: h1 current (bf16)
    const short* __restrict__ hprev,   // recurrent h (bf16)
    const short* __restrict__ Bt,
    const float* __restrict__ bias,
    floatx4* cst,                      // register-resident [6]
    short* __restrict__ hnext,
    short* __restrict__ pool, int t,
    int b, int y0, int x0, short* ldsrec, short* ldsaux, short* ldsH)
{
    constexpr int Ho   = (LAYER == 1) ? H1 : H2;
    constexpr int Wo   = (LAYER == 1) ? W1D : W2D;
    constexpr int NCH  = (LAYER == 1) ? 7 : 12;
    constexpr int REC0 = (LAYER == 1) ? 1 : 6;
    constexpr int HBS  = Ho * Wo * 32;

    const int tid = threadIdx.x;
    const int lane = tid & 63;
    const int fh = tid >> 6;
    const int tx = lane & 15, q = lane >> 4;

    // ---- batched bypass staging: issue all 16B loads, one wait, then LDS ----
    // rec tile: 126 pos (7 rows x 18 cols, SAME-pad) x 4 chunks(16B) = 504
    u32x4 rv[4]; int rof[4]; int rok[4];
    {
        const short* hb0 = hprev + b * HBS;
#pragma unroll
        for (int k = 0; k < 4; ++k) {
            rok[k] = 0; rof[k] = 0;
            int i = tid + k * 128;
            if (i < 504) {
                int p = i >> 2, c4 = i & 3;
                int row = p / 18, col = p - row * 18;
                int y = y0 + row, xx = x0 + col - 1;
                bool inb = (y < Ho) && ((unsigned)xx < (unsigned)Wo);
                const short* ga = inb ? (hb0 + (y * Wo + xx) * 32 + c4 * 8) : hb0;
                GLOAD16(rv[k], ga);
                rok[k] = inb ? 1 : 2;
                rof[k] = p * 40 + c4 * 8;
            }
        }
    }
    u32x4 av[4]; int aof[4]; int aok[4];
    if (LAYER == 2) {
        // input-conv source tile: rows y0..y0+6 (clamped), cols x0..x0+17
        // (OOB cols land in buffer slack; garbage feeds only masked outputs)
        const short* ib0 = xin + b * (H1 * W1D * 32);
#pragma unroll
        for (int k = 0; k < 4; ++k) {
            aok[k] = 0; aof[k] = 0;
            int i = tid + k * 128;
            if (i < 504) {
                int p = i >> 2, c4 = i & 3;
                int row = p / 18, col = p - row * 18;
                int ys = y0 + row; if (ys > H1 - 1) ys = H1 - 1;
                int xs = x0 + col;
                GLOAD16(av[k], ib0 + (ys * W1D + xs) * 32 + c4 * 8);
                aok[k] = 1;
                aof[k] = p * 40 + c4 * 8;
            }
        }
    } else {
        // padded im2col of x chunk 0 (cached float loads, compiler-managed)
        const float* xb0 = xf + b * (TT * 48 * 48 * 3) + t * 6912;
        for (int i = tid; i < 96 * 32; i += 128) {
            int m = i >> 5, k = i & 31;
            short v = 0;
            if (k < 18) {
                int kk = k / 3, cc = k - kk * 3;
                int ky = (kk >= 3) ? 1 : 0, kx = kk - ky * 3;
                int ys = y0 + (m >> 4) + ky; if (ys > 47) ys = 47;
                int xs = x0 + (m & 15) + kx; if (xs > 47) xs = 47;
                v = f2bf(xb0[(ys * 48 + xs) * 3 + cc]);
            }
            ldsaux[m * 40 + k] = v;
        }
    }
    VMWAIT();
#pragma unroll
    for (int k = 0; k < 4; ++k)
        if (rok[k]) *(u32x4*)&ldsrec[rof[k]] = (rok[k] == 1) ? rv[k] : (u32x4)0;
    if (LAYER == 2) {
#pragma unroll
        for (int k = 0; k < 4; ++k)
            if (aok[k]) *(u32x4*)&ldsaux[aof[k]] = av[k];
    }
    __syncthreads();

    const short* Btl = Bt + fh * 2048 + tx * 32 + q * 8;
    floatx4 acc[6][4] = {};   // [a(row)][gate]

#pragma unroll
    for (int c = 0; c < NCH; ++c) {
        short8v bf4[4], af[6];
#pragma unroll
        for (int g = 0; g < 4; ++g)
            bf4[g] = *(const short8v*)(Btl + c * 4096 + g * 512);

        if (LAYER == 1 && c == 0) {
#pragma unroll
            for (int a = 0; a < 6; ++a)
                af[a] = *(const short8v*)&ldsaux[(a * 16 + tx) * 40 + q * 8];
        } else if (LAYER == 2 && c < REC0) {
            int ky = (c >= 3) ? 1 : 0, kx = c - ky * 3;
#pragma unroll
            for (int a = 0; a < 6; ++a)
                af[a] = *(const short8v*)&ldsaux[(((a + ky) * 18 + tx + kx)) * 40 + q * 8];
        } else {
            int kk = c - REC0;
            int ky = (kk >= 3) ? 1 : 0, kx = kk - ky * 3;
#pragma unroll
            for (int a = 0; a < 6; ++a)
                af[a] = *(const short8v*)&ldsrec[(((a + ky) * 18 + tx + kx)) * 40 + q * 8];
        }
#pragma unroll
        for (int a = 0; a < 6; ++a)
#pragma unroll
            for (int g = 0; g < 4; ++g)
                acc[a][g] = __builtin_amdgcn_mfma_f32_16x16x32_bf16(af[a], bf4[g], acc[a][g], 0, 0, 0);
    }

    // ---- fused LSTM epilogue (C layout: M=q*4+r -> x, N=tx(+fh*16) -> f) ----
    const int f = fh * 16 + tx;
    const float bi = bias[f], bfv = bias[32 + f], bcv = bias[64 + f], bov = bias[96 + f];
    float hv[6][4];
#pragma unroll
    for (int a = 0; a < 6; ++a) {
        floatx4 cold = cst[a];
        floatx4 cnew;
#pragma unroll
        for (int r = 0; r < 4; ++r) {
            float ig = hsig(acc[a][0][r] + bi);
            float fg = hsig(acc[a][1][r] + bfv);
            float gg = fmaxf(acc[a][2][r] + bcv, 0.f);
            float og = hsig(acc[a][3][r] + bov);
            float cn = fg * cold[r] + ig * gg;
            cnew[r] = cn;
            short hb = f2bf(og * fmaxf(cn, 0.f));
            ldsH[(a * 16 + q * 4 + r) * 40 + f] = hb;
            hv[a][r] = bf2f(hb);
        }
        cst[a] = cnew;
    }
    __syncthreads();   // ldsH complete (both waves)

    // ---- stream h tile out via bypass 16B stores (skip masked rows/cols) ----
    {
        short* hb_out = hnext + b * HBS;
#pragma unroll
        for (int k = 0; k < 3; ++k) {
            int j = tid + k * 128;                    // 96 pos x 4 chunks(16B)
            int pos = j >> 2, c4 = j & 3;
            int y = y0 + (pos >> 4), xx = x0 + (pos & 15);
            if (y < Ho && xx < Wo) {
                u32x4 w = *(const u32x4*)&ldsH[pos * 40 + c4 * 8];
                GSTORE16(hb_out + (y * Wo + xx) * 32 + c4 * 8, w);
            }
        }
    }

    if (LAYER == 2) {
        // MaxPool(2,2): row pairs (0,1),(2,3),(4,5); col pairs within r
#pragma unroll
        for (int ap = 0; ap < 3; ++ap) {
            int py = y0 / 2 + ap;
#pragma unroll
            for (int rp = 0; rp < 2; ++rp) {
                int px = x0 / 2 + q * 2 + rp;
                if (py < 23 && px < 22) {
                    float m = fmaxf(fmaxf(hv[2 * ap][2 * rp],     hv[2 * ap][2 * rp + 1]),
                                    fmaxf(hv[2 * ap + 1][2 * rp], hv[2 * ap + 1][2 * rp + 1]));
                    pool[(size_t)b * 194304 + ((t * 23 + py) * 22 + px) * 32 + f] = f2bf(m);
                }
            }
        }
    }
}

// ---------------------------------------------------------------------------
// Persistent fused pipeline with fine-grained producer/consumer flags.
// grid = 768 x 128 thr. gid: layer = gid&1 ; b = (gid>>1)&15 ; tile = gid>>5.
// prog1/prog2[(b*24+tile)*16]: number of completed timesteps for that tile.
// Waits per step (block at own time t):
//   L1: halo prog1 >= t (t>=1); WAR: conv-readers prog2 >= t-1 (t>=2)
//   L2: conv prog1 >= t+1 (always); halo prog2 >= t (t>=1)
// DAG in (t,layer) -> no deadlock; 768 blocks all resident (3+/CU).
// ---------------------------------------------------------------------------
__global__ __launch_bounds__(128, 2) void fused_persistent(
    const float* __restrict__ x,
    short* __restrict__ h1a, short* __restrict__ h1b,
    short* __restrict__ h2a, short* __restrict__ h2b,
    const short* __restrict__ Bt1, const short* __restrict__ Bt2,
    const float* __restrict__ b1, const float* __restrict__ b2,
    short* __restrict__ pool, int* prog1, int* prog2)
{
    __shared__ __align__(16) short lds[10080];    // rec [5040] + aux [5040]
    __shared__ __align__(16) short ldsH[3840];    // h-tile staging (stride 40)
    __shared__ int nbl[16];

    const int tid = threadIdx.x;
    int gid   = blockIdx.x;
    int layer = gid & 1;
    int b     = (gid >> 1) & 15;
    int t24   = gid >> 5;
    int ty = t24 / 3, tx3 = t24 - ty * 3;
    int y0 = ty * 6, x0 = tx3 * 16;

    if (tid == 0) {
        int n = 0;   // own-layer halo: 9-neighborhood (covers read + WAR sets)
        for (int dy = -1; dy <= 1; ++dy)
            for (int dx = -1; dx <= 1; ++dx) {
                int ny = ty + dy, nx = tx3 + dx;
                if (ny >= 0 && ny < 8 && nx >= 0 && nx < 3)
                    nbl[n++] = (b * 24 + ny * 3 + nx) << 4;
            }
        nbl[14] = n;
        int m = 0;
        if (layer == 0) {
            // L2 conv-READERS of my h1 tile: {ty-1,ty} x {tx3-1,tx3}
            for (int dy = -1; dy <= 0; ++dy)
                for (int dx = -1; dx <= 0; ++dx) {
                    int ny = ty + dy, nx = tx3 + dx;
                    if (ny >= 0 && nx >= 0)
                        nbl[9 + m++] = (b * 24 + ny * 3 + nx) << 4;
                }
        } else {
            // h1 conv PRODUCERS: {ty, ty+1<=7} x {tx3, tx3+1<=2}
            for (int dy = 0; dy <= 1; ++dy)
                for (int dx = 0; dx <= 1; ++dx) {
                    int ny = ty + dy, nx = tx3 + dx;
                    if (ny < 8 && nx < 3)
                        nbl[9 + m++] = (b * 24 + ny * 3 + nx) << 4;
                }
        }
        nbl[15] = m;
    }
    __syncthreads();
    const int nh = nbl[14], nc = nbl[15];
    const int spin_off = (tid < 14) ? nbl[tid] : 0;
    int* halo_prog  = layer ? prog2 : prog1;
    int* cross_prog = layer ? prog1 : prog2;
    int* myflag = (layer ? prog2 : prog1) + ((b * 24 + t24) << 4);

    floatx4 cst[6];
#pragma unroll
    for (int a = 0; a < 6; ++a) cst[a] = (floatx4)0.f;

    for (int t = 0; t < TT; ++t) {
        // ---- wait on producer / WAR flags (lanes spin, exponential backoff) ----
        {
            const int* pp = nullptr; int tg = 0;
            if (tid < nh) {
                tg = t;                              // halo producers at t-1 done
                if (tg >= 1) pp = halo_prog + spin_off;
            } else if (tid >= 9 && tid < 9 + nc) {
                tg = layer ? (t + 1) : (t - 1);      // L2: conv inputs; L1: WAR
                if (tg >= 1) pp = cross_prog + spin_off;
            }
            if (pp) {
                int slp = 1;
                while (ldflag(pp) < tg) {
                    for (int z = 0; z < slp; ++z) __builtin_amdgcn_s_sleep(8);
                    if (slp < 8) slp += slp;
                }
            }
        }
        __syncthreads();

        if (layer == 0) {
            const short* hprev = (t & 1) ? h1a : h1b;   // h1(t-1)
            short*       hnext = (t & 1) ? h1b : h1a;   // h1(t)
            step_body<1>(x, nullptr, hprev, Bt1, b1, cst, hnext, nullptr, t,
                         b, y0, x0, lds, lds + 5040, ldsH);
        } else {
            const short* h1cur = (t & 1) ? h1b : h1a;   // h1(t)
            const short* hprev = (t & 1) ? h2a : h2b;   // h2(t-1)
            short*       hnext = (t & 1) ? h2b : h2a;   // h2(t)
            step_body<2>(nullptr, h1cur, hprev, Bt2, b2, cst, hnext, pool, t,
                         b, y0, x0, lds, lds + 5040, ldsH);
        }

        // drain this wave's bypass stores, then block-barrier, then publish
        asm volatile("s_waitcnt vmcnt(0)" ::: "memory");
        __syncthreads();
        if (tid == 0) {
            int v = t + 1;
            asm volatile("global_store_dword %0, %1, off sc0 sc1"
                         :: "v"(myflag), "v"(v) : "memory");
        }
    }
}

// ---------------------------------------------------------------------------
__global__ __launch_bounds__(256) void gemv_kernel(
    const short* __restrict__ p, const float* __restrict__ Wd1, float* __restrict__ d1)
{
    int by = blockIdx.y;                 // batch group: 4*by .. 4*by+3
    int k0 = blockIdx.x * 3036;          // 194304 / 64
    float part[4][10];
#pragma unroll
    for (int bb = 0; bb < 4; bb++)
#pragma unroll
        for (int j = 0; j < 10; j++) part[bb][j] = 0.f;

    for (int k = k0 + threadIdx.x; k < k0 + 3036; k += 256) {
        const float* wr = Wd1 + (size_t)k * 10;
        float wv[10];
#pragma unroll
        for (int j = 0; j < 10; j++) wv[j] = wr[j];
#pragma unroll
        for (int bb = 0; bb < 4; bb++) {
            float m = bf2f(p[(size_t)(by * 4 + bb) * 194304 + k]);
#pragma unroll
            for (int j = 0; j < 10; j++) part[bb][j] = fmaf(m, wv[j], part[bb][j]);
        }
    }
    __shared__ float red[4][10][4];
    int lane = threadIdx.x & 63, wv2 = threadIdx.x >> 6;
#pragma unroll
    for (int bb = 0; bb < 4; bb++)
#pragma unroll
        for (int j = 0; j < 10; j++) {
            float v = part[bb][j];
            for (int off = 32; off > 0; off >>= 1) v += __shfl_down(v, off);
            if (lane == 0) red[bb][j][wv2] = v;
        }
    __syncthreads();
    if (threadIdx.x < 40) {
        int bb = threadIdx.x / 10, j = threadIdx.x % 10;
        float s = red[bb][j][0] + red[bb][j][1] + red[bb][j][2] + red[bb][j][3];
        atomicAdd(&d1[(by * 4 + bb) * 10 + j], s);
    }
}

__global__ void final_dense(const float* __restrict__ d1, const float* __restrict__ bd1,
                            const float* __restrict__ Wd2, const float* __restrict__ bd2,
                            float* __restrict__ out)
{
    int b = threadIdx.x;
    if (b < NB) {
        float s = bd2[0];
#pragma unroll
        for (int j = 0; j < 10; j++) s += (d1[b * 10 + j] + bd1[j]) * Wd2[j];
        out[b] = s;
    }
}

// ---------------------------------------------------------------------------
extern "C" void kernel_launch(void* const* d_in, const int* in_sizes, int n_in,
                              void* d_out, int out_size, void* d_ws, size_t ws_size,
                              hipStream_t stream)
{
    const float* x   = (const float*)d_in[0];
    const float* W1s = (const float*)d_in[1];
    const float* U1s = (const float*)d_in[2];
    const float* b1  = (const float*)d_in[3];
    const float* W2s = (const float*)d_in[4];
    const float* U2s = (const float*)d_in[5];
    const float* b2  = (const float*)d_in[6];
    const float* Wd1 = (const float*)d_in[7];
    const float* bd1 = (const float*)d_in[8];
    const float* Wd2 = (const float*)d_in[9];
    const float* bd2 = (const float*)d_in[10];
    float* out = (float*)d_out;

    const int H1N = NB * H1 * W1D * 32;   // 1106944
    const int H2N = NB * H2 * W2D * 32;   // 1036288
    const int SLF = 32, SLB = 8192;
    const int SPAN1 = SLF + H1N + SLB;
    const int SPAN2 = SLF + H2N + SLB;

    short* Bt1 = (short*)d_ws;            // 28672
    short* Bt2 = Bt1 + 28672;             // 49152
    short* p   = Bt2 + 49152;             // 3108864
    short* zr  = p + 3108864;             // ---- zero region ----
    short* h1a = zr + SLF;
    short* h1b = zr + SPAN1 + SLF;
    short* h2a = zr + 2 * SPAN1 + SLF;
    short* h2b = zr + 2 * SPAN1 + SPAN2 + SLF;
    float* d1  = (float*)(zr + 2 * SPAN1 + 2 * SPAN2);
    int* prog1 = (int*)(d1 + 160);        // 384 flags x 16 ints
    int* prog2 = prog1 + 6144;
    size_t zero_bytes = (size_t)(2 * SPAN1 + 2 * SPAN2) * 2 + 160 * 4 + 2 * 6144 * 4;

    hipMemsetAsync(zr, 0, zero_bytes, stream);
    transform_w<<<304, 256, 0, stream>>>(W1s, U1s, W2s, U2s, Bt1, Bt2);

    // single persistent launch: all timesteps inside, flag-based sync
    fused_persistent<<<dim3(NBLK), 128, 0, stream>>>(
        x, h1a, h1b, h2a, h2b, Bt1, Bt2, b1, b2, p, prog1, prog2);

    gemv_kernel<<<dim3(64, 4), 256, 0, stream>>>(p, Wd1, d1);
    final_dense<<<1, 64, 0, stream>>>(d1, bd1, Wd2, bd2, out);
}

// Round 6
// 367.018 us; speedup vs baseline: 3.3624x; 1.0110x over previous
//
#include <hip/hip_runtime.h>
#include <math.h>

// ---------------- problem constants ----------------
#define NB 16
#define TT 12
#define H1 47
#define W1D 46
#define H2 46
#define W2D 44
#define NBLK 768

typedef short short8v __attribute__((ext_vector_type(8)));
typedef float floatx4 __attribute__((ext_vector_type(4)));
typedef unsigned int u32x4 __attribute__((ext_vector_type(4)));

__device__ __forceinline__ short f2bf(float x) {
    unsigned u = __float_as_uint(x);
    u = (u + 0x7FFFu + ((u >> 16) & 1u)) >> 16;   // RNE
    return (short)u;
}
__device__ __forceinline__ float bf2f(short s) {
    return __uint_as_float(((unsigned)(unsigned short)s) << 16);
}
__device__ __forceinline__ float hsig(float z) {
    return fminf(fmaxf(0.2f * z + 0.5f, 0.f), 1.f);
}

// ---- plain (non-atomic) cache-bypassing VMEM ops: coalesce + pipeline, ----
// ---- served at the memory-side LLC which is coherent across XCDs.       ----
#define GLOAD16(dst, addr) \
    asm volatile("global_load_dwordx4 %0, %1, off sc0 sc1" : "=v"(dst) : "v"(addr))
#define GSTORE16(addr, val) \
    asm volatile("global_store_dwordx4 %0, %1, off sc0 sc1" :: "v"(addr), "v"(val) : "memory")
#define VMWAIT() do { asm volatile("s_waitcnt vmcnt(0)" ::: "memory"); \
                      __builtin_amdgcn_sched_barrier(0); } while (0)

__device__ __forceinline__ int ldflag(const int* p) {
    int r;
    asm volatile("global_load_dword %0, %1, off sc0 sc1\n\ts_waitcnt vmcnt(0)"
                 : "=v"(r) : "v"(p) : "memory");
    return r;
}

// ---------------------------------------------------------------------------
// Weights -> MFMA B-fragment layout, bf16.
// flat idx = ((c*2+fh)*4+g)*512 + j*32 + ci ; column = g*32+fh*16+j, k = ci
// ---------------------------------------------------------------------------
__global__ __launch_bounds__(256) void transform_w(
    const float* __restrict__ W1s, const float* __restrict__ U1s,
    const float* __restrict__ W2s, const float* __restrict__ U2s,
    short* __restrict__ Bt1, short* __restrict__ Bt2)
{
    int idx = blockIdx.x * 256 + threadIdx.x;       // 0..77823
    int layer2 = idx >= 28672;
    int i = layer2 ? idx - 28672 : idx;
    int ci = i & 31, j = (i >> 5) & 15, g = (i >> 9) & 3, fh = (i >> 11) & 1, c = i >> 12;
    int col = g * 32 + fh * 16 + j;
    float v = 0.f;
    if (!layer2) {
        if (c == 0) {
            if (ci < 18) { int kk = ci / 3, cc = ci - kk * 3; v = W1s[(kk * 3 + cc) * 128 + col]; }
        } else {
            v = U1s[((c - 1) * 32 + ci) * 128 + col];
        }
    } else {
        if (c < 6) v = W2s[(c * 32 + ci) * 128 + col];
        else       v = U2s[((c - 6) * 32 + ci) * 128 + col];
    }
    (layer2 ? Bt2 : Bt1)[i] = f2bf(v);
}

// ---------------------------------------------------------------------------
// One ConvLSTM timestep body. 128 threads = 2 waves (fh halves).
// Tile 6 rows x 16 cols; wave M=96 (6 row-frags), N=64 (4 gates x 16 f).
// c-state in registers. Cross-block h traffic via 16B bypass asm ops.
// ---------------------------------------------------------------------------
template<int LAYER>
__device__ __forceinline__ void step_body(
    const float* __restrict__ xf,      // L1: raw float x
    const short* __restrict__ xin,     // L2: h1 current (bf16)
    const short* __restrict__ hprev,   // recurrent h (bf16)
    const short* __restrict__ Bt,
    const float* __restrict__ bias,
    floatx4* cst,                      // register-resident [6]
    short* __restrict__ hnext,
    short* __restrict__ pool, int t,
    int b, int y0, int x0, short* ldsrec, short* ldsaux, short* ldsH)
{
    constexpr int Ho   = (LAYER == 1) ? H1 : H2;
    constexpr int Wo   = (LAYER == 1) ? W1D : W2D;
    constexpr int NCH  = (LAYER == 1) ? 7 : 12;
    constexpr int REC0 = (LAYER == 1) ? 1 : 6;
    constexpr int HBS  = Ho * Wo * 32;

    const int tid = threadIdx.x;
    const int lane = tid & 63;
    const int fh = tid >> 6;
    const int tx = lane & 15, q = lane >> 4;

    // ---- batched bypass staging: issue all 16B loads, one wait, then LDS ----
    // rec tile: 126 pos (7 rows x 18 cols, SAME-pad) x 4 chunks(16B) = 504
    u32x4 rv[4]; int rof[4]; int rok[4];
    {
        const short* hb0 = hprev + b * HBS;
#pragma unroll
        for (int k = 0; k < 4; ++k) {
            rok[k] = 0; rof[k] = 0;
            int i = tid + k * 128;
            if (i < 504) {
                int p = i >> 2, c4 = i & 3;
                int row = p / 18, col = p - row * 18;
                int y = y0 + row, xx = x0 + col - 1;
                bool inb = (y < Ho) && ((unsigned)xx < (unsigned)Wo);
                const short* ga = inb ? (hb0 + (y * Wo + xx) * 32 + c4 * 8) : hb0;
                GLOAD16(rv[k], ga);
                rok[k] = inb ? 1 : 2;
                rof[k] = p * 40 + c4 * 8;
            }
        }
    }
    u32x4 av[4]; int aof[4]; int aok[4];
    if (LAYER == 2) {
        // input-conv source tile: rows y0..y0+6 (clamped), cols x0..x0+17
        // (OOB cols land in buffer slack; garbage feeds only masked outputs)
        const short* ib0 = xin + b * (H1 * W1D * 32);
#pragma unroll
        for (int k = 0; k < 4; ++k) {
            aok[k] = 0; aof[k] = 0;
            int i = tid + k * 128;
            if (i < 504) {
                int p = i >> 2, c4 = i & 3;
                int row = p / 18, col = p - row * 18;
                int ys = y0 + row; if (ys > H1 - 1) ys = H1 - 1;
                int xs = x0 + col;
                GLOAD16(av[k], ib0 + (ys * W1D + xs) * 32 + c4 * 8);
                aok[k] = 1;
                aof[k] = p * 40 + c4 * 8;
            }
        }
    } else {
        // padded im2col of x chunk 0 (cached float loads, compiler-managed)
        const float* xb0 = xf + b * (TT * 48 * 48 * 3) + t * 6912;
        for (int i = tid; i < 96 * 32; i += 128) {
            int m = i >> 5, k = i & 31;
            short v = 0;
            if (k < 18) {
                int kk = k / 3, cc = k - kk * 3;
                int ky = (kk >= 3) ? 1 : 0, kx = kk - ky * 3;
                int ys = y0 + (m >> 4) + ky; if (ys > 47) ys = 47;
                int xs = x0 + (m & 15) + kx; if (xs > 47) xs = 47;
                v = f2bf(xb0[(ys * 48 + xs) * 3 + cc]);
            }
            ldsaux[m * 40 + k] = v;
        }
    }
    VMWAIT();
#pragma unroll
    for (int k = 0; k < 4; ++k)
        if (rok[k]) *(u32x4*)&ldsrec[rof[k]] = (rok[k] == 1) ? rv[k] : (u32x4)0;
    if (LAYER == 2) {
#pragma unroll
        for (int k = 0; k < 4; ++k)
            if (aok[k]) *(u32x4*)&ldsaux[aof[k]] = av[k];
    }
    __syncthreads();

    const short* Btl = Bt + fh * 2048 + tx * 32 + q * 8;
    floatx4 acc[6][4] = {};   // [a(row)][gate]

#pragma unroll
    for (int c = 0; c < NCH; ++c) {
        short8v bf4[4], af[6];
#pragma unroll
        for (int g = 0; g < 4; ++g)
            bf4[g] = *(const short8v*)(Btl + c * 4096 + g * 512);

        if (LAYER == 1 && c == 0) {
#pragma unroll
            for (int a = 0; a < 6; ++a)
                af[a] = *(const short8v*)&ldsaux[(a * 16 + tx) * 40 + q * 8];
        } else if (LAYER == 2 && c < REC0) {
            int ky = (c >= 3) ? 1 : 0, kx = c - ky * 3;
#pragma unroll
            for (int a = 0; a < 6; ++a)
                af[a] = *(const short8v*)&ldsaux[(((a + ky) * 18 + tx + kx)) * 40 + q * 8];
        } else {
            int kk = c - REC0;
            int ky = (kk >= 3) ? 1 : 0, kx = kk - ky * 3;
#pragma unroll
            for (int a = 0; a < 6; ++a)
                af[a] = *(const short8v*)&ldsrec[(((a + ky) * 18 + tx + kx)) * 40 + q * 8];
        }
#pragma unroll
        for (int a = 0; a < 6; ++a)
#pragma unroll
            for (int g = 0; g < 4; ++g)
                acc[a][g] = __builtin_amdgcn_mfma_f32_16x16x32_bf16(af[a], bf4[g], acc[a][g], 0, 0, 0);
    }

    // ---- fused LSTM epilogue (C layout: M=q*4+r -> x, N=tx(+fh*16) -> f) ----
    const int f = fh * 16 + tx;
    const float bi = bias[f], bfv = bias[32 + f], bcv = bias[64 + f], bov = bias[96 + f];
    float hv[6][4];
#pragma unroll
    for (int a = 0; a < 6; ++a) {
        floatx4 cold = cst[a];
        floatx4 cnew;
#pragma unroll
        for (int r = 0; r < 4; ++r) {
            float ig = hsig(acc[a][0][r] + bi);
            float fg = hsig(acc[a][1][r] + bfv);
            float gg = fmaxf(acc[a][2][r] + bcv, 0.f);
            float og = hsig(acc[a][3][r] + bov);
            float cn = fg * cold[r] + ig * gg;
            cnew[r] = cn;
            short hb = f2bf(og * fmaxf(cn, 0.f));
            ldsH[(a * 16 + q * 4 + r) * 40 + f] = hb;
            hv[a][r] = bf2f(hb);
        }
        cst[a] = cnew;
    }
    __syncthreads();   // ldsH complete (both waves)

    // ---- stream h tile out via bypass 16B stores (skip masked rows/cols) ----
    {
        short* hb_out = hnext + b * HBS;
#pragma unroll
        for (int k = 0; k < 3; ++k) {
            int j = tid + k * 128;                    // 96 pos x 4 chunks(16B)
            int pos = j >> 2, c4 = j & 3;
            int y = y0 + (pos >> 4), xx = x0 + (pos & 15);
            if (y < Ho && xx < Wo) {
                u32x4 w = *(const u32x4*)&ldsH[pos * 40 + c4 * 8];
                GSTORE16(hb_out + (y * Wo + xx) * 32 + c4 * 8, w);
            }
        }
    }

    if (LAYER == 2) {
        // MaxPool(2,2): row pairs (0,1),(2,3),(4,5); col pairs within r
#pragma unroll
        for (int ap = 0; ap < 3; ++ap) {
            int py = y0 / 2 + ap;
#pragma unroll
            for (int rp = 0; rp < 2; ++rp) {
                int px = x0 / 2 + q * 2 + rp;
                if (py < 23 && px < 22) {
                    float m = fmaxf(fmaxf(hv[2 * ap][2 * rp],     hv[2 * ap][2 * rp + 1]),
                                    fmaxf(hv[2 * ap + 1][2 * rp], hv[2 * ap + 1][2 * rp + 1]));
                    pool[(size_t)b * 194304 + ((t * 23 + py) * 22 + px) * 32 + f] = f2bf(m);
                }
            }
        }
    }
}

// ---------------------------------------------------------------------------
// Persistent fused pipeline with fine-grained producer/consumer flags.
// grid = 768 x 128 thr. gid: layer = gid&1 ; b = (gid>>1)&15 ; tile = gid>>5.
// prog1/prog2[(b*24+tile)*16] = completed timesteps of that tile's block.
// h1/h2 are 3-SLOT rings (slot = t mod 3) -> WAR slack = 2 steps, so L1
// free-runs ahead of L2 and the two layer wavefronts overlap.
// Waits of block at step t:
//  L1: halo prog1 >= t (data+WAR on h1 ring vs neighbor L1 readers);
//      cross (L2 aux readers of the slot being overwritten) prog2 >= t-2.
//  L2: cross (h1 producers of slot t%3) prog1 >= t+1 (data, pre-satisfied
//      in steady state); halo prog2 >= t (data+WAR on h2 ring).
// DAG in (t,layer) -> acyclic; 768 blocks all co-resident -> no deadlock.
// ---------------------------------------------------------------------------
__global__ __launch_bounds__(128, 2) void fused_persistent(
    const float* __restrict__ x,
    short* __restrict__ h1s0, short* __restrict__ h1s1, short* __restrict__ h1s2,
    short* __restrict__ h2s0, short* __restrict__ h2s1, short* __restrict__ h2s2,
    const short* __restrict__ Bt1, const short* __restrict__ Bt2,
    const float* __restrict__ b1, const float* __restrict__ b2,
    short* __restrict__ pool, int* prog1, int* prog2)
{
    __shared__ __align__(16) short lds[10080];    // rec [5040] + aux [5040]
    __shared__ __align__(16) short ldsH[3840];    // h-tile staging (stride 40)
    __shared__ int nbl[16];

    const int tid = threadIdx.x;
    int gid   = blockIdx.x;
    int layer = gid & 1;
    int b     = (gid >> 1) & 15;
    int t24   = gid >> 5;
    int ty = t24 / 3, tx3 = t24 - ty * 3;
    int y0 = ty * 6, x0 = tx3 * 16;

    if (tid == 0) {
        int n = 0;   // own-layer halo: 9-neighborhood (covers read + WAR sets)
        for (int dy = -1; dy <= 1; ++dy)
            for (int dx = -1; dx <= 1; ++dx) {
                int ny = ty + dy, nx = tx3 + dx;
                if (ny >= 0 && ny < 8 && nx >= 0 && nx < 3)
                    nbl[n++] = (b * 24 + ny * 3 + nx) << 4;
            }
        nbl[14] = n;
        int m = 0;
        if (layer == 0) {
            // L2 conv-READERS of my h1 tile: {ty-1,ty} x {tx3-1,tx3}
            for (int dy = -1; dy <= 0; ++dy)
                for (int dx = -1; dx <= 0; ++dx) {
                    int ny = ty + dy, nx = tx3 + dx;
                    if (ny >= 0 && nx >= 0)
                        nbl[9 + m++] = (b * 24 + ny * 3 + nx) << 4;
                }
        } else {
            // h1 conv PRODUCERS: {ty, ty+1<=7} x {tx3, tx3+1<=2}
            for (int dy = 0; dy <= 1; ++dy)
                for (int dx = 0; dx <= 1; ++dx) {
                    int ny = ty + dy, nx = tx3 + dx;
                    if (ny < 8 && nx < 3)
                        nbl[9 + m++] = (b * 24 + ny * 3 + nx) << 4;
                }
        }
        nbl[15] = m;
    }
    __syncthreads();
    const int nh = nbl[14], nc = nbl[15];
    const int spin_off = (tid < 14) ? nbl[tid] : 0;
    int* halo_prog  = layer ? prog2 : prog1;
    int* cross_prog = layer ? prog1 : prog2;
    int* myflag = (layer ? prog2 : prog1) + ((b * 24 + t24) << 4);

    floatx4 cst[6];
#pragma unroll
    for (int a = 0; a < 6; ++a) cst[a] = (floatx4)0.f;

    for (int t = 0; t < TT; ++t) {
        // ---- wait on producer / WAR flags (lanes spin, capped backoff) ----
        {
            const int* pp = nullptr; int tg = 0;
            if (tid < nh) {
                tg = t;                              // halo producers at t-1 done
                if (tg >= 1) pp = halo_prog + spin_off;
            } else if (tid >= 9 && tid < 9 + nc) {
                tg = layer ? (t + 1) : (t - 2);      // L2: conv inputs; L1: WAR(3-slot)
                if (tg >= 1) pp = cross_prog + spin_off;
            }
            if (pp) {
                int slp = 1;
                while (ldflag(pp) < tg) {
                    for (int z = 0; z < slp; ++z) __builtin_amdgcn_s_sleep(8);
                    if (slp < 2) slp += slp;         // cap ~1k cycles
                }
            }
        }
        __syncthreads();

        int sw = t % 3, sr = (t + 2) % 3;   // write slot, read slot (t-1)
        short* h1w = (sw == 0) ? h1s0 : ((sw == 1) ? h1s1 : h1s2);
        short* h1r = (sr == 0) ? h1s0 : ((sr == 1) ? h1s1 : h1s2);
        short* h2w = (sw == 0) ? h2s0 : ((sw == 1) ? h2s1 : h2s2);
        short* h2r = (sr == 0) ? h2s0 : ((sr == 1) ? h2s1 : h2s2);

        if (layer == 0) {
            step_body<1>(x, nullptr, h1r, Bt1, b1, cst, h1w, nullptr, t,
                         b, y0, x0, lds, lds + 5040, ldsH);
        } else {
            step_body<2>(nullptr, h1w, h2r, Bt2, b2, cst, h2w, pool, t,
                         b, y0, x0, lds, lds + 5040, ldsH);
        }

        // drain this wave's bypass stores, then block-barrier, then publish
        asm volatile("s_waitcnt vmcnt(0)" ::: "memory");
        __syncthreads();
        if (tid == 0) {
            int v = t + 1;
            asm volatile("global_store_dword %0, %1, off sc0 sc1"
                         :: "v"(myflag), "v"(v) : "memory");
        }
    }
}

// ---------------------------------------------------------------------------
__global__ __launch_bounds__(256) void gemv_kernel(
    const short* __restrict__ p, const float* __restrict__ Wd1, float* __restrict__ d1)
{
    int by = blockIdx.y;                 // batch group: 4*by .. 4*by+3
    int k0 = blockIdx.x * 3036;          // 194304 / 64
    float part[4][10];
#pragma unroll
    for (int bb = 0; bb < 4; bb++)
#pragma unroll
        for (int j = 0; j < 10; j++) part[bb][j] = 0.f;

    for (int k = k0 + threadIdx.x; k < k0 + 3036; k += 256) {
        const float* wr = Wd1 + (size_t)k * 10;
        float wv[10];
#pragma unroll
        for (int j = 0; j < 10; j++) wv[j] = wr[j];
#pragma unroll
        for (int bb = 0; bb < 4; bb++) {
            float m = bf2f(p[(size_t)(by * 4 + bb) * 194304 + k]);
#pragma unroll
            for (int j = 0; j < 10; j++) part[bb][j] = fmaf(m, wv[j], part[bb][j]);
        }
    }
    __shared__ float red[4][10][4];
    int lane = threadIdx.x & 63, wv2 = threadIdx.x >> 6;
#pragma unroll
    for (int bb = 0; bb < 4; bb++)
#pragma unroll
        for (int j = 0; j < 10; j++) {
            float v = part[bb][j];
            for (int off = 32; off > 0; off >>= 1) v += __shfl_down(v, off);
            if (lane == 0) red[bb][j][wv2] = v;
        }
    __syncthreads();
    if (threadIdx.x < 40) {
        int bb = threadIdx.x / 10, j = threadIdx.x % 10;
        float s = red[bb][j][0] + red[bb][j][1] + red[bb][j][2] + red[bb][j][3];
        atomicAdd(&d1[(by * 4 + bb) * 10 + j], s);
    }
}

__global__ void final_dense(const float* __restrict__ d1, const float* __restrict__ bd1,
                            const float* __restrict__ Wd2, const float* __restrict__ bd2,
                            float* __restrict__ out)
{
    int b = threadIdx.x;
    if (b < NB) {
        float s = bd2[0];
#pragma unroll
        for (int j = 0; j < 10; j++) s += (d1[b * 10 + j] + bd1[j]) * Wd2[j];
        out[b] = s;
    }
}

// ---------------------------------------------------------------------------
extern "C" void kernel_launch(void* const* d_in, const int* in_sizes, int n_in,
                              void* d_out, int out_size, void* d_ws, size_t ws_size,
                              hipStream_t stream)
{
    const float* x   = (const float*)d_in[0];
    const float* W1s = (const float*)d_in[1];
    const float* U1s = (const float*)d_in[2];
    const float* b1  = (const float*)d_in[3];
    const float* W2s = (const float*)d_in[4];
    const float* U2s = (const float*)d_in[5];
    const float* b2  = (const float*)d_in[6];
    const float* Wd1 = (const float*)d_in[7];
    const float* bd1 = (const float*)d_in[8];
    const float* Wd2 = (const float*)d_in[9];
    const float* bd2 = (const float*)d_in[10];
    float* out = (float*)d_out;

    const int H1N = NB * H1 * W1D * 32;   // 1106944
    const int H2N = NB * H2 * W2D * 32;   // 1036288
    const int SLF = 32, SLB = 8192;
    const int SPAN1 = SLF + H1N + SLB;
    const int SPAN2 = SLF + H2N + SLB;

    short* Bt1 = (short*)d_ws;            // 28672
    short* Bt2 = Bt1 + 28672;             // 49152
    short* p   = Bt2 + 49152;             // 3108864
    short* zr  = p + 3108864;             // ---- zero region ----
    short* h1s0 = zr + 0 * SPAN1 + SLF;
    short* h1s1 = zr + 1 * SPAN1 + SLF;
    short* h1s2 = zr + 2 * SPAN1 + SLF;
    short* h2bb = zr + 3 * SPAN1;
    short* h2s0 = h2bb + 0 * SPAN2 + SLF;
    short* h2s1 = h2bb + 1 * SPAN2 + SLF;
    short* h2s2 = h2bb + 2 * SPAN2 + SLF;
    float* d1  = (float*)(zr + 3 * SPAN1 + 3 * SPAN2);
    int* prog1 = (int*)(d1 + 160);        // 384 flags x 16 ints
    int* prog2 = prog1 + 6144;
    size_t zero_bytes = (size_t)(3 * SPAN1 + 3 * SPAN2) * 2 + 160 * 4 + 2 * 6144 * 4;

    hipMemsetAsync(zr, 0, zero_bytes, stream);
    transform_w<<<304, 256, 0, stream>>>(W1s, U1s, W2s, U2s, Bt1, Bt2);

    // single persistent launch: all timesteps inside, flag-based sync
    fused_persistent<<<dim3(NBLK), 128, 0, stream>>>(
        x, h1s0, h1s1, h1s2, h2s0, h2s1, h2s2, Bt1, Bt2, b1, b2, p, prog1, prog2);

    gemv_kernel<<<dim3(64, 4), 256, 0, stream>>>(p, Wd1, d1);
    final_dense<<<1, 64, 0, stream>>>(d1, bd1, Wd2, bd2, out);
}